// Round 6
// baseline (1170.676 us; speedup 1.0000x reference)
//
#include <hip/hip_runtime.h>
#include <hip/hip_bf16.h>
#include <stdint.h>

// ---------------------------------------------------------------------------
// AdaptiveAngleConv: 5 angles of (bilinear deform-sample -> 3x3 conv)
// x: (2,256,64,64) f32, weight: (256,256,3,3) f32
// out: 5 x (2,256,190,190) f32 concatenated
// Conv = implicit GEMM, round-1-proven loop structure (stage -> compute ->
// one __syncthreads, compiler-scheduled interior), upgraded with:
//   - 32x32x16 bf16 MFMA (fewer instrs, faster shape)
//   - conflict-free k-major LDS layout [c16][px][16B] (no swizzle needed)
//   - BK=32 dbuf (32KB) + slim 2-pass epilogue (34KB) -> 4 blocks/CU
//   - tap-inner K order (L2-resident tap re-reads)
// ---------------------------------------------------------------------------

#define S2F 1.41421356237309515f

__constant__ float c_ox[5][9] = {
  {0.f,0.f,0.f,0.f,0.f,0.f,0.f,0.f,0.f},
  {1.f-S2F, 1.f-S2F*0.5f, 1.f, -S2F*0.5f, 0.f, S2F*0.5f, -1.f, S2F*0.5f-1.f, S2F-1.f},
  {0.f,1.f,2.f,-1.f,0.f,1.f,-2.f,-1.f,0.f},
  {1.f, 1.f+S2F*0.5f, 1.f+S2F, -S2F*0.5f, 0.f, S2F*0.5f, -1.f-S2F, -1.f-S2F*0.5f, -1.f},
  {2.f,2.f,2.f,0.f,0.f,0.f,-2.f,-2.f,-2.f}
};
__constant__ float c_oy[5][9] = {
  {0.f,0.f,0.f,0.f,0.f,0.f,0.f,0.f,0.f},
  {1.f, S2F*0.5f, S2F-1.f, 1.f-S2F*0.5f, 0.f, S2F*0.5f-1.f, 1.f-S2F, -S2F*0.5f, -1.f},
  {2.f,1.f,0.f,1.f,0.f,-1.f,0.f,-1.f,-2.f},
  {1.f+S2F, S2F*0.5f, -1.f, 1.f+S2F*0.5f, 0.f, -1.f-S2F*0.5f, 1.f, -S2F*0.5f, 1.f+S2F},
  {2.f,0.f,-2.f,2.f,0.f,-2.f,2.f,0.f,-2.f}
};

typedef __bf16 bf16x8_t __attribute__((ext_vector_type(8)));
typedef float f32x4_t __attribute__((ext_vector_type(4)));
typedef float f32x16_t __attribute__((ext_vector_type(16)));

typedef const __attribute__((address_space(1))) void* as1cp;
typedef __attribute__((address_space(3))) void* as3p;

__device__ __forceinline__ void gload16(const void* g, void* l) {
  __builtin_amdgcn_global_load_lds((as1cp)g, (as3p)l, 16, 0, 0);
}

// x NCHW (2,256,64,64) -> xT NHWC (2,64,64,256) f32
__global__ void k_transpose(const float* __restrict__ x, float* __restrict__ xT) {
  const int v = blockIdx.x, u = blockIdx.y, b = blockIdx.z;
  const int ic = threadIdx.x;
  xT[(((b*64 + u)*64 + v)*256) + ic] =
      x[(((b*256 + ic)*64 + u)*64) + v];
}

// weight OIHW (256,256,3,3) f32 -> wb (9,256,256)=[t][oc][ic] bf16
__global__ void k_wconv(const float* __restrict__ w, __hip_bfloat16* __restrict__ wb) {
  const int tid = blockIdx.x*256 + threadIdx.x;   // < 9*256*256
  const int t = tid >> 16;
  const int rem = tid & 65535;
  const int oc = rem >> 8;
  const int ic = rem & 255;
  wb[tid] = __float2bfloat16(w[(oc*256 + ic)*9 + t]);
}

// bilinear deform-sample -> xo bf16 NHWC [(a)][b][192][192][256]
__global__ void k_sample(const float* __restrict__ xT,
                         __hip_bfloat16* __restrict__ xo, int a0)
{
  const int aidx = a0 + blockIdx.z;
  __hip_bfloat16* xoa = xo + (size_t)blockIdx.z * (2ull*192*192*256);

  const int tid = threadIdx.x;           // 256
  const int ic = (tid & 63) * 4;
  const int j = blockIdx.x*4 + (tid >> 6);
  const int i = blockIdx.y;

  const int a = i / 3, r = i - 3*a;
  const int bc = j / 3, s = j - 3*bc;
  const int n = r*3 + s;
  const float px = (float)(a + r) + c_ox[aidx][n];
  const float py = (float)(bc + s) + c_oy[aidx][n];
  const float fx = floorf(px), fy = floorf(py);
  const float pxc = fminf(fmaxf(px, 0.f), 65.f);
  const float pyc = fminf(fmaxf(py, 0.f), 65.f);
  const int qlx = (int)fminf(fmaxf(fx,      0.f), 65.f);
  const int qrx = (int)fminf(fmaxf(fx + 1.f, 0.f), 65.f);
  const int qly = (int)fminf(fmaxf(fy,      0.f), 65.f);
  const int qry = (int)fminf(fmaxf(fy + 1.f, 0.f), 65.f);
  const float wlx = 1.f + (float)qlx - pxc;
  const float wrx = 1.f - (float)qrx + pxc;
  const float wly = 1.f + (float)qly - pyc;
  const float wry = 1.f - (float)qry + pyc;
  const float glt = wlx*wly, grb = wrx*wry, glb = wlx*wry, grt = wrx*wly;

  const bool inxl = (qlx >= 1) && (qlx <= 64);
  const bool inxr = (qrx >= 1) && (qrx <= 64);
  const bool inyl = (qly >= 1) && (qly <= 64);
  const bool inyr = (qry >= 1) && (qry <= 64);

  const f32x4_t zero = (f32x4_t){0.f,0.f,0.f,0.f};
  #pragma unroll
  for (int b = 0; b < 2; ++b) {
    const float* xb = xT + (size_t)b * (64*64*256);
    f32x4_t vlt = (inxl && inyl) ? *(const f32x4_t*)&xb[((qlx-1)*64 + (qly-1))*256 + ic] : zero;
    f32x4_t vrb = (inxr && inyr) ? *(const f32x4_t*)&xb[((qrx-1)*64 + (qry-1))*256 + ic] : zero;
    f32x4_t vlb = (inxl && inyr) ? *(const f32x4_t*)&xb[((qlx-1)*64 + (qry-1))*256 + ic] : zero;
    f32x4_t vrt = (inxr && inyl) ? *(const f32x4_t*)&xb[((qrx-1)*64 + (qly-1))*256 + ic] : zero;
    ushort4 pk;
    float v0 = glt*vlt[0] + grb*vrb[0] + glb*vlb[0] + grt*vrt[0];
    float v1 = glt*vlt[1] + grb*vrb[1] + glb*vlb[1] + grt*vrt[1];
    float v2 = glt*vlt[2] + grb*vrb[2] + glb*vlb[2] + grt*vrt[2];
    float v3 = glt*vlt[3] + grb*vrb[3] + glb*vlb[3] + grt*vrt[3];
    pk.x = __hip_bfloat16_raw(__float2bfloat16(v0)).x;
    pk.y = __hip_bfloat16_raw(__float2bfloat16(v1)).x;
    pk.z = __hip_bfloat16_raw(__float2bfloat16(v2)).x;
    pk.w = __hip_bfloat16_raw(__float2bfloat16(v3)).x;
    *(ushort4*)&xoa[(((size_t)b*192 + i)*192 + j)*256 + ic] = pk;
  }
}

// ---------------------------------------------------------------------------
// conv: implicit GEMM. grid.x = nab*570 (bijective XCD chunking).
// Block: 128 px (2 i-rows x 64 j-cols) x 128 oc; 256 thr / 4 waves (2Mx2N);
// per-wave 64x64 via 2x2 of mfma_f32_32x32x16_bf16.
// K = 9 taps x 256 ic, BK=32, tap-inner (kk = icg*9 + tap), 72 steps.
// LDS: buf{0,1} @ {0,16384}: A [c16 4][px 128][16B] 8KB | B [c16][oc][16B] 8KB
// Epilogue: 2 oc-half passes through f32[64][134] (34304 B).
// ---------------------------------------------------------------------------
__global__ __launch_bounds__(256, 4) void k_conv5(
    const __hip_bfloat16* __restrict__ xo,   // [ab][192][192][256] bf16
    const __hip_bfloat16* __restrict__ wb,   // [9][256][256] bf16 (t,oc,ic)
    float* __restrict__ out)                 // + ab*9241600 : [256][190][190]
{
  __shared__ __align__(16) char smem[34816];

  const int nblk = gridDim.x;
  const int id = blockIdx.x;
  const int qq = nblk >> 3, rr = nblk & 7;
  const int xcd = id & 7, pos = id >> 3;
  const int swz = (xcd < rr ? xcd*(qq+1) : rr*(qq+1) + (xcd-rr)*qq) + pos;
  const int ab = swz / 570;
  const int rem = swz - ab*570;
  const int it = rem / 6;
  const int r6 = rem - it*6;
  const int jt = r6 >> 1, oct = r6 & 1;
  const int i0 = it*2, j0 = jt*64, oc0 = oct*128;

  const int tid = threadIdx.x;
  const int w = tid >> 6, l = tid & 63;
  const int wm = w >> 1, wn = w & 1;

  const char* xob = (const char*)(xo + (size_t)ab * 9437184u);
  const char* wbc = (const char*)wb;

  // frag read base offsets within a buffer half: [c16][row][16B]
  const int aoff = (l >> 5)*2048 + (wm*64 + (l & 31))*16;
  const int boff = (l >> 5)*2048 + (wn*64 + (l & 31))*16;

  // staging constants (wave w covers chunks w and w+4 of A and of B)
  const int c16lo = (w >> 1)*16;            // byte offset of this wave's c16
  const int pxh   = w & 1;

  auto stage = [&](int kk2, int buf) {
    const int icg = kk2 / 9;                // ic group of 32 (tap-inner order)
    const int tap = kk2 - icg*9;
    const int ki = (tap >= 6) ? 2 : ((tap >= 3) ? 1 : 0);
    const int kj = tap - ki*3;
    char* Ad = smem + buf*16384;
    char* Bd = Ad + 8192;
    const int i1 = i0 + pxh + ki;           // <= 191 always
    int jj = j0 + l + kj; if (jj > 191) jj = 191;   // garbage cols, never stored
    const char* abase = xob + (size_t)((((i1*192 + jj) << 8) + icg*32) * 2);
    gload16(abase + c16lo,      Ad + w*1024);
    gload16(abase + c16lo + 32, Ad + (w + 4)*1024);
    const int oca = oc0 + pxh*64 + l;
    const char* bbase = wbc + (size_t)((((tap << 16) + oca*256 + icg*32)) * 2);
    gload16(bbase + c16lo,      Bd + w*1024);
    gload16(bbase + c16lo + 32, Bd + (w + 4)*1024);
  };

  f32x16_t acc[2][2];
  #pragma unroll
  for (int mf = 0; mf < 2; ++mf)
    #pragma unroll
    for (int nf = 0; nf < 2; ++nf)
      #pragma unroll
      for (int v = 0; v < 16; ++v)
        acc[mf][nf][v] = 0.f;

  stage(0, 0);
  __syncthreads();

  for (int kk = 0; kk < 72; ++kk) {
    const int cur = kk & 1;
    if (kk < 71) stage(kk + 1, cur ^ 1);
    const char* Ab = smem + cur*16384;
    const char* Bb = Ab + 8192;
    #pragma unroll
    for (int ks = 0; ks < 2; ++ks) {
      bf16x8_t a0 = *(const bf16x8_t*)(Ab + aoff + ks*4096);
      bf16x8_t a1 = *(const bf16x8_t*)(Ab + aoff + ks*4096 + 512);
      bf16x8_t b0 = *(const bf16x8_t*)(Bb + boff + ks*4096);
      bf16x8_t b1 = *(const bf16x8_t*)(Bb + boff + ks*4096 + 512);
      acc[0][0] = __builtin_amdgcn_mfma_f32_32x32x16_bf16(a0, b0, acc[0][0], 0, 0, 0);
      acc[0][1] = __builtin_amdgcn_mfma_f32_32x32x16_bf16(a0, b1, acc[0][1], 0, 0, 0);
      acc[1][0] = __builtin_amdgcn_mfma_f32_32x32x16_bf16(a1, b0, acc[1][0], 0, 0, 0);
      acc[1][1] = __builtin_amdgcn_mfma_f32_32x32x16_bf16(a1, b1, acc[1][1], 0, 0, 0);
    }
    __syncthreads();
  }

  // --- epilogue: 2 oc-half passes via eps f32[64][134] ---
  // C/D 32x32 layout: px = (reg&3) + 8*(reg>>2) + 4*(l>>5), oc = l&31
  float* eps = (float*)smem;
  float* outab = out + (size_t)ab * 9241600u;
  const int ocr = tid >> 2, sub = tid & 3;
  const int iS = i0 + (sub >> 1);
  const int jbase = j0 + (sub & 1)*32;
  const int l31 = l & 31, l5 = l >> 5;

  #pragma unroll
  for (int h = 0; h < 2; ++h) {
    if (wn == h) {
      #pragma unroll
      for (int mf = 0; mf < 2; ++mf)
        #pragma unroll
        for (int nf = 0; nf < 2; ++nf) {
          const int row = nf*32 + l31;
          const int colb = wm*64 + mf*32 + l5*4;
          #pragma unroll
          for (int qv = 0; qv < 4; ++qv) {
            float* d = &eps[row*134 + colb + qv*8];
            d[0] = acc[mf][nf][qv*4 + 0];
            d[1] = acc[mf][nf][qv*4 + 1];
            d[2] = acc[mf][nf][qv*4 + 2];
            d[3] = acc[mf][nf][qv*4 + 3];
          }
        }
    }
    __syncthreads();
    {
      float* dst = outab + (size_t)(oc0 + h*64 + ocr)*36100u + iS*190 + jbase;
      const float* src = eps + ocr*134 + sub*32;
      int kmax = 32;
      if (jt == 2 && (sub & 1)) kmax = 30;     // j = 160+k < 190
      for (int k = 0; k < kmax; k += 2)
        *(float2*)(dst + k) = make_float2(src[k], src[k + 1]);
    }
    if (h == 0) __syncthreads();
  }
}

extern "C" void kernel_launch(void* const* d_in, const int* in_sizes, int n_in,
                              void* d_out, int out_size, void* d_ws, size_t ws_size,
                              hipStream_t stream)
{
  const float* x = (const float*)d_in[0];
  const float* w = (const float*)d_in[1];
  float* out = (float*)d_out;

  char* ws = (char*)d_ws;
  float*          xT = (float*)ws;                         // 8,388,608 B
  __hip_bfloat16* wb = (__hip_bfloat16*)(ws + 8388608);    // 1,179,648 B
  __hip_bfloat16* xo = (__hip_bfloat16*)(ws + 9568256);    // 5 or 1 x 37,748,736 B

  const bool merged = (ws_size >= 198311936ull);

  k_transpose<<<dim3(64, 64, 2), 256, 0, stream>>>(x, xT);
  k_wconv<<<2304, 256, 0, stream>>>(w, wb);

  if (merged) {
    k_sample<<<dim3(48, 192, 5), 256, 0, stream>>>(xT, xo, 0);
    k_conv5<<<5700, 256, 0, stream>>>(xo, wb, out);
  } else {
    for (int aidx = 0; aidx < 5; ++aidx) {
      k_sample<<<dim3(48, 192, 1), 256, 0, stream>>>(xT, xo, aidx);
      k_conv5<<<1140, 256, 0, stream>>>(xo, wb, out + (size_t)aidx * 18483200u);
    }
  }
}

// Round 7
// 936.034 us; speedup vs baseline: 1.2507x; 1.2507x over previous
//
#include <hip/hip_runtime.h>
#include <hip/hip_bf16.h>
#include <stdint.h>

// ---------------------------------------------------------------------------
// AdaptiveAngleConv: 5 angles of (bilinear deform-sample -> 3x3 conv)
// x: (2,256,64,64) f32, weight: (256,256,3,3) f32
// out: 5 x (2,256,190,190) f32 concatenated
//
// Conv = window implicit GEMM:
//  - per ic-group (64 ic) stage a 4row x 72col x 128B xo window in LDS ONCE;
//    all 9 taps are shifted views -> zero barriers inside the tap loop,
//    only 4 barriers per block (one per ic-group), dbuf windows.
//  - B (weights) L2-resident: direct global->VGPR fragment loads (wb2 packed
//    so each frag load is 2x contiguous 512B). No LDS for B.
//  - per-wave tile 128px x 32oc (1Mx4N): B never duplicated across waves.
//  - A-read swizzle slot ^= col&7 (involution on both stage-src and read).
// ---------------------------------------------------------------------------

#define S2F 1.41421356237309515f

__constant__ float c_ox[5][9] = {
  {0.f,0.f,0.f,0.f,0.f,0.f,0.f,0.f,0.f},
  {1.f-S2F, 1.f-S2F*0.5f, 1.f, -S2F*0.5f, 0.f, S2F*0.5f, -1.f, S2F*0.5f-1.f, S2F-1.f},
  {0.f,1.f,2.f,-1.f,0.f,1.f,-2.f,-1.f,0.f},
  {1.f, 1.f+S2F*0.5f, 1.f+S2F, -S2F*0.5f, 0.f, S2F*0.5f, -1.f-S2F, -1.f-S2F*0.5f, -1.f},
  {2.f,2.f,2.f,0.f,0.f,0.f,-2.f,-2.f,-2.f}
};
__constant__ float c_oy[5][9] = {
  {0.f,0.f,0.f,0.f,0.f,0.f,0.f,0.f,0.f},
  {1.f, S2F*0.5f, S2F-1.f, 1.f-S2F*0.5f, 0.f, S2F*0.5f-1.f, 1.f-S2F, -S2F*0.5f, -1.f},
  {2.f,1.f,0.f,1.f,0.f,-1.f,0.f,-1.f,-2.f},
  {1.f+S2F, S2F*0.5f, -1.f, 1.f+S2F*0.5f, 0.f, -1.f-S2F*0.5f, 1.f, -S2F*0.5f, 1.f+S2F},
  {2.f,0.f,-2.f,2.f,0.f,-2.f,2.f,0.f,-2.f}
};

typedef __bf16 bf16x8_t __attribute__((ext_vector_type(8)));
typedef float f32x4_t __attribute__((ext_vector_type(4)));
typedef float f32x16_t __attribute__((ext_vector_type(16)));

typedef const __attribute__((address_space(1))) void* as1cp;
typedef __attribute__((address_space(3))) void* as3p;

__device__ __forceinline__ void gload16(const void* g, void* l) {
  __builtin_amdgcn_global_load_lds((as1cp)g, (as3p)l, 16, 0, 0);
}

// x NCHW (2,256,64,64) -> xT NHWC (2,64,64,256) f32
__global__ void k_transpose(const float* __restrict__ x, float* __restrict__ xT) {
  const int v = blockIdx.x, u = blockIdx.y, b = blockIdx.z;
  const int ic = threadIdx.x;
  xT[(((b*64 + u)*64 + v)*256) + ic] =
      x[(((b*256 + ic)*64 + u)*64) + v];
}

// weight OIHW (256,256,3,3) f32 -> wb2 packed bf16:
// wb2[tap][icg][ks][hi][oc 256][e 8], entry = W[oc][icg*64+ks*16+hi*8+e][tap]
__global__ void k_wconv(const float* __restrict__ w, __hip_bfloat16* __restrict__ wb2) {
  const int g = blockIdx.x*256 + threadIdx.x;   // < 9*4*4*2*256*8 = 589824
  const int e  = g & 7;
  const int oc = (g >> 3) & 255;
  const int r  = g >> 11;                       // 0..287
  const int hi  = r & 1;
  const int ks  = (r >> 1) & 3;
  const int icg = (r >> 3) & 3;
  const int tap = r >> 5;                       // 0..8
  const int ic = icg*64 + ks*16 + hi*8 + e;
  wb2[g] = __float2bfloat16(w[(oc*256 + ic)*9 + tap]);
}

// bilinear deform-sample -> xo bf16 NHWC [(a)][b][192][192][256]
__global__ void k_sample(const float* __restrict__ xT,
                         __hip_bfloat16* __restrict__ xo, int a0)
{
  const int aidx = a0 + blockIdx.z;
  __hip_bfloat16* xoa = xo + (size_t)blockIdx.z * (2ull*192*192*256);

  const int tid = threadIdx.x;           // 256
  const int ic = (tid & 63) * 4;
  const int j = blockIdx.x*4 + (tid >> 6);
  const int i = blockIdx.y;

  const int a = i / 3, r = i - 3*a;
  const int bc = j / 3, s = j - 3*bc;
  const int n = r*3 + s;
  const float px = (float)(a + r) + c_ox[aidx][n];
  const float py = (float)(bc + s) + c_oy[aidx][n];
  const float fx = floorf(px), fy = floorf(py);
  const float pxc = fminf(fmaxf(px, 0.f), 65.f);
  const float pyc = fminf(fmaxf(py, 0.f), 65.f);
  const int qlx = (int)fminf(fmaxf(fx,      0.f), 65.f);
  const int qrx = (int)fminf(fmaxf(fx + 1.f, 0.f), 65.f);
  const int qly = (int)fminf(fmaxf(fy,      0.f), 65.f);
  const int qry = (int)fminf(fmaxf(fy + 1.f, 0.f), 65.f);
  const float wlx = 1.f + (float)qlx - pxc;
  const float wrx = 1.f - (float)qrx + pxc;
  const float wly = 1.f + (float)qly - pyc;
  const float wry = 1.f - (float)qry + pyc;
  const float glt = wlx*wly, grb = wrx*wry, glb = wlx*wry, grt = wrx*wly;

  const bool inxl = (qlx >= 1) && (qlx <= 64);
  const bool inxr = (qrx >= 1) && (qrx <= 64);
  const bool inyl = (qly >= 1) && (qly <= 64);
  const bool inyr = (qry >= 1) && (qry <= 64);

  const f32x4_t zero = (f32x4_t){0.f,0.f,0.f,0.f};
  #pragma unroll
  for (int b = 0; b < 2; ++b) {
    const float* xb = xT + (size_t)b * (64*64*256);
    f32x4_t vlt = (inxl && inyl) ? *(const f32x4_t*)&xb[((qlx-1)*64 + (qly-1))*256 + ic] : zero;
    f32x4_t vrb = (inxr && inyr) ? *(const f32x4_t*)&xb[((qrx-1)*64 + (qry-1))*256 + ic] : zero;
    f32x4_t vlb = (inxl && inyr) ? *(const f32x4_t*)&xb[((qlx-1)*64 + (qry-1))*256 + ic] : zero;
    f32x4_t vrt = (inxr && inyl) ? *(const f32x4_t*)&xb[((qrx-1)*64 + (qly-1))*256 + ic] : zero;
    ushort4 pk;
    float v0 = glt*vlt[0] + grb*vrb[0] + glb*vlb[0] + grt*vrt[0];
    float v1 = glt*vlt[1] + grb*vrb[1] + glb*vlb[1] + grt*vrt[1];
    float v2 = glt*vlt[2] + grb*vrb[2] + glb*vlb[2] + grt*vrt[2];
    float v3 = glt*vlt[3] + grb*vrb[3] + glb*vlb[3] + grt*vrt[3];
    pk.x = __hip_bfloat16_raw(__float2bfloat16(v0)).x;
    pk.y = __hip_bfloat16_raw(__float2bfloat16(v1)).x;
    pk.z = __hip_bfloat16_raw(__float2bfloat16(v2)).x;
    pk.w = __hip_bfloat16_raw(__float2bfloat16(v3)).x;
    *(ushort4*)&xoa[(((size_t)b*192 + i)*192 + j)*256 + ic] = pk;
  }
}

// ---------------------------------------------------------------------------
// conv: window implicit GEMM. grid.x = nab*570 (bijective XCD chunking).
// Block: 128 px (2 out rows x 64 cols) x 128 oc; 256 thr / 4 waves.
// Wave n owns oc stripe n*32..n*32+31; per-wave tile 128px x 32oc
// (4 M-frags of mfma_f32_32x32x16_bf16, acc = 64 VGPR).
// LDS: A window dbuf: [buf2][4 rows][72 cols][8 slots][16B] = 2 x 36864 B.
// K loop: 4 ic-groups x (9 taps x 4 ks) with ONE barrier per ic-group.
// ---------------------------------------------------------------------------
__global__ __launch_bounds__(256, 2) void k_conv6(
    const __hip_bfloat16* __restrict__ xo,   // [ab][192][192][256] bf16
    const __hip_bfloat16* __restrict__ wb2,  // packed (see k_wconv)
    float* __restrict__ out)                 // + ab*9241600 : [256][190][190]
{
  __shared__ __align__(16) char smem[73728];

  const int nblk = gridDim.x;
  const int id = blockIdx.x;
  const int qq = nblk >> 3, rr = nblk & 7;
  const int xcd = id & 7, pos = id >> 3;
  const int swz = (xcd < rr ? xcd*(qq+1) : rr*(qq+1) + (xcd-rr)*qq) + pos;
  const int ab = swz / 570;
  const int rem = swz - ab*570;
  const int it = rem / 6;                     // 0..94
  const int r6 = rem - it*6;
  const int jt = r6 >> 1, oct = r6 & 1;
  const int i0 = it*2, j0 = jt*64, oc0 = oct*128;

  const int tid = threadIdx.x;
  const int w = tid >> 6, l = tid & 63;
  const int l31 = l & 31, hi = l >> 5;

  const char* xob = (const char*)(xo + (size_t)ab * 9437184u);
  const char* wbc = (const char*)wb2;

  // --- per-lane staging sources: 9 chunks/thread, chunk c = (k*4+w)*64 + l ---
  // chunk c -> (r = c/576, p = (c%576)>>3, s = c&7); LDS byte = c*16 (linear)
  int sOff[9];
  #pragma unroll
  for (int k = 0; k < 9; ++k) {
    const int c = (k*4 + w)*64 + l;
    const int r = c / 576;
    const int cr = c - r*576;
    const int p = cr >> 3, s = cr & 7;
    int xj = j0 + p; if (xj > 191) xj = 191;       // pad cols (never read)
    sOff[k] = (((i0 + r)*192 + xj)*256 + ((s ^ (p & 7))*8))*2;
  }
  const int dstOff[1] = {0};
  (void)dstOff;

  // B-frag byte offset inside wb2 for (tap,icg,ks): + per-lane part
  const int bLane = (hi*256 + oc0 + w*32 + l31)*16;

  f32x16_t acc[4];
  #pragma unroll
  for (int mf = 0; mf < 4; ++mf)
    #pragma unroll
    for (int v = 0; v < 16; ++v)
      acc[mf][v] = 0.f;

  const int colA = l31;        // window col base for mf even
  const int colB = 32 + l31;   // for mf odd

  auto stage = [&](int icg, int buf) {
    char* dbase = smem + buf*36864;
    #pragma unroll
    for (int k = 0; k < 9; ++k)
      gload16(xob + (size_t)(sOff[k] + icg*128), dbase + (k*4 + w)*1024);
  };

  stage(0, 0);
  __syncthreads();

  #pragma unroll
  for (int icg = 0; icg < 4; ++icg) {
    const int buf = icg & 1;
    if (icg < 3) stage(icg + 1, buf ^ 1);

    const char* Ab = smem + buf*36864;
    #pragma unroll
    for (int tap = 0; tap < 9; ++tap) {
      const int ki = (tap >= 6) ? 2 : ((tap >= 3) ? 1 : 0);
      const int kj = tap - ki*3;
      const int pc0 = colA + kj, pc1 = colB + kj;
      const int sw0 = (pc0 & 7), sw1 = (pc1 & 7);
      const char* wt = wbc + (size_t)((tap*4 + icg)*4) * 8192;
      #pragma unroll
      for (int ks = 0; ks < 4; ++ks) {
        const bf16x8_t bfr = *(const bf16x8_t*)(wt + ks*8192 + bLane);
        const int t = ks*2 + hi;
        const int a00 = ((ki    )*72 + pc0)*128 + ((t ^ sw0)*16);
        const int a01 = ((ki    )*72 + pc1)*128 + ((t ^ sw1)*16);
        const int a10 = ((ki + 1)*72 + pc0)*128 + ((t ^ sw0)*16);
        const int a11 = ((ki + 1)*72 + pc1)*128 + ((t ^ sw1)*16);
        const bf16x8_t af0 = *(const bf16x8_t*)(Ab + a00);
        const bf16x8_t af1 = *(const bf16x8_t*)(Ab + a01);
        const bf16x8_t af2 = *(const bf16x8_t*)(Ab + a10);
        const bf16x8_t af3 = *(const bf16x8_t*)(Ab + a11);
        acc[0] = __builtin_amdgcn_mfma_f32_32x32x16_bf16(af0, bfr, acc[0], 0, 0, 0);
        acc[1] = __builtin_amdgcn_mfma_f32_32x32x16_bf16(af1, bfr, acc[1], 0, 0, 0);
        acc[2] = __builtin_amdgcn_mfma_f32_32x32x16_bf16(af2, bfr, acc[2], 0, 0, 0);
        acc[3] = __builtin_amdgcn_mfma_f32_32x32x16_bf16(af3, bfr, acc[3], 0, 0, 0);
      }
    }
    __syncthreads();
  }

  // --- epilogue: LDS transpose eps f32[oc 128][px 128] stride 129 (66048 B) ---
  // C/D 32x32 layout: oc = l&31, px_in_frag = (v&3) + 8*(v>>2) + 4*hi
  float* eps = (float*)smem;
  const int erow = (w*32 + l31)*129;
  #pragma unroll
  for (int mf = 0; mf < 4; ++mf) {
    const int pxb = mf*32 + 4*hi;
    #pragma unroll
    for (int qv = 0; qv < 4; ++qv) {
      float* d = &eps[erow + pxb + 8*qv];
      d[0] = acc[mf][qv*4 + 0];
      d[1] = acc[mf][qv*4 + 1];
      d[2] = acc[mf][qv*4 + 2];
      d[3] = acc[mf][qv*4 + 3];
    }
  }
  __syncthreads();

  float* outab = out + (size_t)ab * 9241600u;
  const int ocr = tid >> 1, half = tid & 1;
  const int iS = i0 + half;                       // <= 189 always
  const int kmax = (jt == 2) ? 62 : 64;
  float* dst = outab + (size_t)(oc0 + ocr)*36100u + iS*190 + j0;
  const float* src = eps + ocr*129 + half*64;
  for (int k = 0; k < kmax; k += 2)
    *(float2*)(dst + k) = make_float2(src[k], src[k + 1]);
}

extern "C" void kernel_launch(void* const* d_in, const int* in_sizes, int n_in,
                              void* d_out, int out_size, void* d_ws, size_t ws_size,
                              hipStream_t stream)
{
  const float* x = (const float*)d_in[0];
  const float* w = (const float*)d_in[1];
  float* out = (float*)d_out;

  char* ws = (char*)d_ws;
  float*          xT  = (float*)ws;                        // 8,388,608 B
  __hip_bfloat16* wb2 = (__hip_bfloat16*)(ws + 8388608);   // 1,179,648 B
  __hip_bfloat16* xo  = (__hip_bfloat16*)(ws + 9568256);   // 5 or 1 x 37,748,736 B

  const bool merged = (ws_size >= 198311936ull);

  k_transpose<<<dim3(64, 64, 2), 256, 0, stream>>>(x, xT);
  k_wconv<<<2304, 256, 0, stream>>>(w, wb2);

  if (merged) {
    k_sample<<<dim3(48, 192, 5), 256, 0, stream>>>(xT, xo, 0);
    k_conv6<<<5700, 256, 0, stream>>>(xo, wb2, out);
  } else {
    for (int aidx = 0; aidx < 5; ++aidx) {
      k_sample<<<dim3(48, 192, 1), 256, 0, stream>>>(xT, xo, aidx);
      k_conv6<<<1140, 256, 0, stream>>>(xo, wb2, out + (size_t)aidx * 18483200u);
    }
  }
}